// Round 11
// baseline (160.380 us; speedup 1.0000x reference)
//
#include <hip/hip_runtime.h>
#include <hip/hip_bf16.h>

// NTM single step. B=256, D=256, H=512, M=64, N=2048, S=3, SHIFTS=(1,0,-1)
#define Bb 256
#define Hh 512
#define Mm 64
#define Nn 2048

typedef __attribute__((ext_vector_type(8))) short bf16x8;
typedef __attribute__((ext_vector_type(4))) float f32x4;
typedef __attribute__((ext_vector_type(4))) unsigned short u16x4;
typedef __attribute__((ext_vector_type(8))) unsigned short u16x8;

static __device__ __forceinline__ short f2bf(float f) {
    unsigned u = __float_as_uint(f);
    unsigned r = (u + 0x7FFFu + ((u >> 16) & 1u)) >> 16;
    return (short)r;
}
static __device__ __forceinline__ float bf2f(unsigned short u) {
    return __uint_as_float(((unsigned)u) << 16);
}

// ---------------- kernel 1: blocks 0..255 read-path head params; 256..1087 convW
__global__ __launch_bounds__(256) void headparams_convW_kernel(
    const float* __restrict__ h,
    const float* __restrict__ Wk, const float* __restrict__ bk,
    const float* __restrict__ Wc, const float* __restrict__ bc,
    const float* __restrict__ Ws, const float* __restrict__ bs,
    float* __restrict__ kk, float* __restrict__ par,
    const float* __restrict__ W_ih, const float* __restrict__ W_hh,
    short* __restrict__ Wb)
{
    if (blockIdx.x >= 256) {
        unsigned g = (blockIdx.x - 256) * 256 + threadIdx.x;   // 212992 chunks
        unsigned j = g / 104u;
        unsigned kq = (g - j * 104u) * 8u;
        const float* src = (kq < 320u) ? (W_ih + (size_t)j * 320 + kq)
                                       : (W_hh + (size_t)j * 512 + (kq - 320u));
        float4 a = ((const float4*)src)[0];
        float4 c = ((const float4*)src)[1];
        bf16x8 o;
        o[0] = f2bf(a.x); o[1] = f2bf(a.y); o[2] = f2bf(a.z); o[3] = f2bf(a.w);
        o[4] = f2bf(c.x); o[5] = f2bf(c.y); o[6] = f2bf(c.z); o[7] = f2bf(c.w);
        *(bf16x8*)(Wb + (size_t)j * 832 + kq) = o;
        return;
    }
    int b = blockIdx.x;
    __shared__ float hs[Hh];
    __shared__ float red[6];
    __shared__ float skk[Mm];
    const float* hb = h + (size_t)b * Hh;
    for (int i = threadIdx.x; i < Hh; i += 256) hs[i] = hb[i];
    __syncthreads();
    int m = threadIdx.x >> 2, sub = threadIdx.x & 3;
    {
        const float* w = Wk + (size_t)m * Hh + sub * 128;
        const float* hh = hs + sub * 128;
        float acc = 0.f;
        #pragma unroll 8
        for (int k = 0; k < 128; ++k) acc += hh[k] * w[k];
        acc += __shfl_xor(acc, 1, 64);
        acc += __shfl_xor(acc, 2, 64);
        if (sub == 0) {
            float v = tanhf(acc + bk[m]);
            kk[(size_t)b * Mm + m] = v;
            skk[m] = v;
        }
    }
    if (threadIdx.x < 24) {
        int o = threadIdx.x >> 2, su = threadIdx.x & 3;
        const float* w = ((o < 3) ? (Wc + (size_t)o * Hh) : (Ws + (size_t)(o - 3) * Hh)) + su * 128;
        const float* hh = hs + su * 128;
        float acc = 0.f;
        #pragma unroll 8
        for (int k = 0; k < 128; ++k) acc += hh[k] * w[k];
        acc += __shfl_xor(acc, 1, 64);
        acc += __shfl_xor(acc, 2, 64);
        if (su == 0) red[o] = acc + ((o < 3) ? bc[o] : bs[o - 3]);
    }
    __syncthreads();
    if (threadIdx.x == 0) {
        float beta  = fmaxf(red[0], 0.f) + 1e-4f;
        float g     = 1.f / (1.f + __expf(-red[1]));
        float gamma = fmaxf(red[2], 0.f) + 1.0001f;
        float l0 = red[3], l1 = red[4], l2 = red[5];
        float mx = fmaxf(l0, fmaxf(l1, l2));
        float e0 = __expf(l0 - mx), e1 = __expf(l1 - mx), e2 = __expf(l2 - mx);
        float inv = 1.f / (e0 + e1 + e2);
        float ssq = 0.f;
        #pragma unroll
        for (int i = 0; i < Mm; ++i) ssq += skk[i] * skk[i];
        float* p = par + (size_t)b * 8;
        p[0] = beta; p[1] = g; p[2] = gamma;
        p[3] = e0 * inv; p[4] = e1 * inv; p[5] = e2 * inv;
        p[6] = sqrtf(ssq);
    }
}

// ---------------- kernel 2: mem f32 -> bf16 copy + read cosine (wide)
__global__ __launch_bounds__(256) void convM_cos_kernel(
    const float* __restrict__ mem, const float* __restrict__ kk,
    const float* __restrict__ par, float* __restrict__ cosv,
    short* __restrict__ memb)
{
    int b  = blockIdx.x >> 3;
    int n0 = (blockIdx.x & 7) << 8;
    int w  = threadIdx.x >> 6;
    int l  = threadIdx.x & 63;
    int m4 = l & 15;
    int rq = l >> 4;

    float4 kv = ((const float4*)(kk + (size_t)b * Mm))[m4];
    float kn = par[(size_t)b * 8 + 6];
    const f32x4* mb4 = (const f32x4*)(mem + (size_t)b * Nn * Mm);
    short* ob = memb + (size_t)b * Nn * Mm;

    #pragma unroll
    for (int q = 0; q < 16; ++q) {
        int n = n0 + w * 64 + q * 4 + rq;
        f32x4 v = __builtin_nontemporal_load(mb4 + (size_t)n * 16 + m4);
        u16x4 o;
        o[0] = (unsigned short)f2bf(v[0]); o[1] = (unsigned short)f2bf(v[1]);
        o[2] = (unsigned short)f2bf(v[2]); o[3] = (unsigned short)f2bf(v[3]);
        *(u16x4*)(ob + (size_t)n * 64 + m4 * 4) = o;   // keep cached (reused 3x)
        float dot = v[0] * kv.x + v[1] * kv.y + v[2] * kv.z + v[3] * kv.w;
        float ss  = v[0] * v[0] + v[1] * v[1] + v[2] * v[2] + v[3] * v[3];
        dot += __shfl_xor(dot, 1, 64); ss += __shfl_xor(ss, 1, 64);
        dot += __shfl_xor(dot, 2, 64); ss += __shfl_xor(ss, 2, 64);
        dot += __shfl_xor(dot, 4, 64); ss += __shfl_xor(ss, 4, 64);
        dot += __shfl_xor(dot, 8, 64); ss += __shfl_xor(ss, 8, 64);
        if (m4 == 0) cosv[(size_t)b * Nn + n] = dot / fmaxf(kn * sqrtf(ss), 1e-8f);
    }
}

// ---------------- generic address finalize (per-batch): softmax/interp/shift/pow -> head
__global__ __launch_bounds__(1024) void address_kernel(
    const float* __restrict__ cosv, const float* __restrict__ par,
    const float* __restrict__ prev, float* __restrict__ outh)
{
    int b = blockIdx.x;
    int t = threadIdx.x;
    int w = t >> 6, l = t & 63;
    __shared__ float csh[Nn];
    __shared__ float redw[16];

    const float* pv = par + (size_t)b * 8;
    float beta = pv[0], g = pv[1], gamma = pv[2];
    float s0 = pv[3], s1 = pv[4], s2 = pv[5];

    float v0 = beta * cosv[(size_t)b * Nn + t];
    float v1 = beta * cosv[(size_t)b * Nn + t + 1024];
    float mx = fmaxf(v0, v1);
    #pragma unroll
    for (int msk = 1; msk < 64; msk <<= 1) mx = fmaxf(mx, __shfl_xor(mx, msk, 64));
    if (l == 0) redw[w] = mx;
    __syncthreads();
    mx = redw[0];
    #pragma unroll
    for (int i = 1; i < 16; ++i) mx = fmaxf(mx, redw[i]);
    float e0 = __expf(v0 - mx), e1 = __expf(v1 - mx);
    float sum = e0 + e1;
    #pragma unroll
    for (int msk = 1; msk < 64; msk <<= 1) sum += __shfl_xor(sum, msk, 64);
    __syncthreads();
    if (l == 0) redw[w] = sum;
    __syncthreads();
    sum = 0.f;
    #pragma unroll
    for (int i = 0; i < 16; ++i) sum += redw[i];
    float invs = 1.f / sum;
    const float* pb = prev + (size_t)b * Nn;
    float i0 = g * e0 * invs + (1.f - g) * pb[t];
    float i1 = g * e1 * invs + (1.f - g) * pb[t + 1024];
    csh[t] = i0; csh[t + 1024] = i1;
    __syncthreads();
    int n1 = t + 1024;
    float c0 = s0 * csh[(t + 1) & (Nn - 1)] + s1 * i0 + s2 * csh[(t - 1) & (Nn - 1)];
    float c1 = s0 * csh[(n1 + 1) & (Nn - 1)] + s1 * i1 + s2 * csh[(n1 - 1) & (Nn - 1)];
    float p0 = exp2f(gamma * __log2f(c0));
    float p1 = exp2f(gamma * __log2f(c1));
    float osum = p0 + p1;
    #pragma unroll
    for (int msk = 1; msk < 64; msk <<= 1) osum += __shfl_xor(osum, msk, 64);
    __syncthreads();
    if (l == 0) redw[w] = osum;
    __syncthreads();
    osum = 0.f;
    #pragma unroll
    for (int i = 0; i < 16; ++i) osum += redw[i];
    float inv2 = 1.f / osum;
    outh[(size_t)b * Nn + t] = p0 * inv2;
    outh[(size_t)b * Nn + n1] = p1 * inv2;
}

// ---------------- wide M_read partial: block (b, ch) sums 256 rows -> psc[b][ch][64]
__global__ __launch_bounds__(256) void mread_partial_kernel(
    const short* __restrict__ memb, const float* __restrict__ rhead,
    float* __restrict__ psc)
{
    int b = blockIdx.x >> 3, ch = blockIdx.x & 7;
    int t = threadIdx.x;
    int m8 = t & 7, r = t >> 3;          // r 0..31
    const short* mb = memb + (size_t)b * Nn * Mm;
    const float* hb = rhead + (size_t)b * Nn;
    float acc[8] = {};
    #pragma unroll
    for (int it = 0; it < 8; ++it) {
        int n = ch * 256 + it * 32 + r;
        float wgt = hb[n];
        u16x8 uv = *(const u16x8*)(mb + (size_t)n * 64 + m8 * 8);
        #pragma unroll
        for (int j = 0; j < 8; ++j) acc[j] += wgt * bf2f(uv[j]);
    }
    __shared__ float red[32][64];        // 8 KB
    #pragma unroll
    for (int j = 0; j < 8; ++j) red[r][m8 * 8 + j] = acc[j];
    __syncthreads();
    if (t < 64) {
        float s = 0.f;
        #pragma unroll
        for (int rr = 0; rr < 32; ++rr) s += red[rr][t];
        psc[((size_t)b * 8 + ch) * 64 + t] = s;
    }
}

// ---------------- reduce M_read partials + build A row (bf16)
__global__ __launch_bounds__(128) void convA_kernel(
    const float* __restrict__ psc, const float* __restrict__ inp,
    const float* __restrict__ h, short* __restrict__ Ab)
{
    int b = blockIdx.x;
    int t = threadIdx.x;
    __shared__ float mrdL[Mm];
    if (t < 64) {
        float s = 0.f;
        #pragma unroll
        for (int ch = 0; ch < 8; ++ch) s += psc[((size_t)b * 8 + ch) * 64 + t];
        mrdL[t] = s;
    }
    __syncthreads();
    if (t < 104) {
        int kq = t * 8;
        float v[8];
        if (kq < 256) {
            const float* s = inp + (size_t)b * 256 + kq;
            #pragma unroll
            for (int i = 0; i < 8; ++i) v[i] = s[i];
        } else if (kq < 320) {
            #pragma unroll
            for (int i = 0; i < 8; ++i) v[i] = mrdL[kq - 256 + i];
        } else {
            const float* s = h + (size_t)b * 512 + (kq - 320);
            #pragma unroll
            for (int i = 0; i < 8; ++i) v[i] = s[i];
        }
        bf16x8 o;
        #pragma unroll
        for (int i = 0; i < 8; ++i) o[i] = f2bf(v[i]);
        *(bf16x8*)(Ab + (size_t)b * 832 + kq) = o;
    }
}

// ---------------- kernel 4: MFMA GEMM, LDS-free (operands L2/L3-resident)
__global__ __launch_bounds__(256) void lstm_gemm_mfma(
    const short* __restrict__ Ab, const short* __restrict__ Wb,
    const float* __restrict__ b_ih, const float* __restrict__ b_hh,
    float* __restrict__ z)
{
    int t = threadIdx.x;
    int r0 = blockIdx.x * 64, c0 = blockIdx.y * 64;
    int w = t >> 6, l = t & 63;
    int wr = (w >> 1) * 32, wc = (w & 1) * 32;
    int lr = l & 15, kb = (l >> 4) * 8;

    const short* A0 = Ab + (size_t)(r0 + wr + lr) * 832 + kb;
    const short* A1 = A0 + 16 * 832;
    const short* B0 = Wb + (size_t)(c0 + wc + lr) * 832 + kb;
    const short* B1 = B0 + 16 * 832;

    f32x4 acc00 = {0.f, 0.f, 0.f, 0.f}, acc01 = {0.f, 0.f, 0.f, 0.f};
    f32x4 acc10 = {0.f, 0.f, 0.f, 0.f}, acc11 = {0.f, 0.f, 0.f, 0.f};

    #pragma unroll 2
    for (int kt = 0; kt < 26; ++kt) {
        int k0 = kt * 32;
        bf16x8 a0 = *(const bf16x8*)(A0 + k0);
        bf16x8 a1 = *(const bf16x8*)(A1 + k0);
        bf16x8 b0 = *(const bf16x8*)(B0 + k0);
        bf16x8 b1 = *(const bf16x8*)(B1 + k0);
        acc00 = __builtin_amdgcn_mfma_f32_16x16x32_bf16(a0, b0, acc00, 0, 0, 0);
        acc01 = __builtin_amdgcn_mfma_f32_16x16x32_bf16(a0, b1, acc01, 0, 0, 0);
        acc10 = __builtin_amdgcn_mfma_f32_16x16x32_bf16(a1, b0, acc10, 0, 0, 0);
        acc11 = __builtin_amdgcn_mfma_f32_16x16x32_bf16(a1, b1, acc11, 0, 0, 0);
    }
    int rq = (l >> 4) * 4;
    #pragma unroll
    for (int q = 0; q < 4; ++q) {
        int row0 = r0 + wr + rq + q;
        int col0 = c0 + wc + lr;
        z[(size_t)row0 * 2048 + col0] = acc00[q] + b_ih[col0] + b_hh[col0];
        z[(size_t)row0 * 2048 + col0 + 16] = acc01[q] + b_ih[col0 + 16] + b_hh[col0 + 16];
        z[(size_t)(row0 + 16) * 2048 + col0] = acc10[q] + b_ih[col0] + b_hh[col0];
        z[(size_t)(row0 + 16) * 2048 + col0 + 16] = acc11[q] + b_ih[col0 + 16] + b_hh[col0 + 16];
    }
}

// ---------------- kernel 5: gates -> h_t,c_t + write head params + wvec (per-batch)
__global__ __launch_bounds__(1024) void gates_wparams_kernel(
    const float* __restrict__ z, const float* __restrict__ c_tm1,
    const float* __restrict__ Wk, const float* __restrict__ bk,
    const float* __restrict__ Wc, const float* __restrict__ bc,
    const float* __restrict__ Ws, const float* __restrict__ bs,
    const float* __restrict__ W_w, const float* __restrict__ b_w,
    float* __restrict__ h_out, float* __restrict__ c_out,
    float* __restrict__ kk, float* __restrict__ par, float* __restrict__ ea)
{
    int b = blockIdx.x;
    int t = threadIdx.x;
    __shared__ float hs[Hh];
    __shared__ float red6[6];
    __shared__ float skk[Mm];

    if (t < 512) {
        const float* zb = z + (size_t)b * 2048;
        float zi = zb[t], zf = zb[512 + t], zg = zb[1024 + t], zo = zb[1536 + t];
        float si = 1.f / (1.f + __expf(-zi));
        float sf = 1.f / (1.f + __expf(-zf));
        float so = 1.f / (1.f + __expf(-zo));
        float ct = sf * c_tm1[(size_t)b * 512 + t] + si * tanhf(zg);
        float ht = so * tanhf(ct);
        c_out[(size_t)b * 512 + t] = ct;
        h_out[(size_t)b * 512 + t] = ht;
        hs[t] = ht;
    }
    __syncthreads();

    if (t < 256) {
        int m = t >> 2, sub = t & 3;
        const float* wv = Wk + (size_t)m * Hh + sub * 128;
        const float* hh = hs + sub * 128;
        float acc = 0.f;
        #pragma unroll 8
        for (int k = 0; k < 128; ++k) acc += hh[k] * wv[k];
        acc += __shfl_xor(acc, 1, 64);
        acc += __shfl_xor(acc, 2, 64);
        if (sub == 0) {
            float v = tanhf(acc + bk[m]);
            skk[m] = v;
            kk[(size_t)b * Mm + m] = v;
        }
    } else if (t < 280) {
        int o = (t - 256) >> 2, su = t & 3;
        const float* wv = ((o < 3) ? (Wc + (size_t)o * Hh) : (Ws + (size_t)(o - 3) * Hh)) + su * 128;
        const float* hh = hs + su * 128;
        float acc = 0.f;
        #pragma unroll 8
        for (int k = 0; k < 128; ++k) acc += hh[k] * wv[k];
        acc += __shfl_xor(acc, 1, 64);
        acc += __shfl_xor(acc, 2, 64);
        if (su == 0) red6[o] = acc + ((o < 3) ? bc[o] : bs[o - 3]);
    } else if (t >= 512) {
        int o = (t - 512) >> 2, su = t & 3;
        const float* wv = W_w + (size_t)o * Hh + su * 128;
        const float* hh = hs + su * 128;
        float acc = 0.f;
        #pragma unroll 8
        for (int k = 0; k < 128; ++k) acc += hh[k] * wv[k];
        acc += __shfl_xor(acc, 1, 64);
        acc += __shfl_xor(acc, 2, 64);
        if (su == 0) {
            float v = acc + b_w[o];
            ea[(size_t)b * 128 + o] = (o < Mm) ? (1.f / (1.f + __expf(-v))) : tanhf(v);
        }
    }
    __syncthreads();
    if (t < 64) {
        float v = skk[t];
        float ssq = v * v;
        #pragma unroll
        for (int msk = 1; msk < 64; msk <<= 1) ssq += __shfl_xor(ssq, msk, 64);
        if (t == 0) {
            float* p = par + (size_t)b * 8;
            p[6] = sqrtf(ssq);
            p[0] = fmaxf(red6[0], 0.f) + 1e-4f;
            p[1] = 1.f / (1.f + __expf(-red6[1]));
            p[2] = fmaxf(red6[2], 0.f) + 1.0001f;
            float l0 = red6[3], l1 = red6[4], l2 = red6[5];
            float mx = fmaxf(l0, fmaxf(l1, l2));
            float e0 = __expf(l0 - mx), e1 = __expf(l1 - mx), e2 = __expf(l2 - mx);
            float inv = 1.f / (e0 + e1 + e2);
            p[3] = e0 * inv; p[4] = e1 * inv; p[5] = e2 * inv;
        }
    }
}

// ---------------- wide write cosine from bf16 memb (2048 blocks)
__global__ __launch_bounds__(256) void wcos_kernel(
    const short* __restrict__ memb, const float* __restrict__ kk,
    const float* __restrict__ par, float* __restrict__ cosv)
{
    int b = blockIdx.x >> 3, ch = blockIdx.x & 7;
    int w = threadIdx.x >> 6, l = threadIdx.x & 63;
    int m8 = l & 7, rg = l >> 3;
    float kv8[8];
    {
        const float* kp = kk + (size_t)b * Mm + m8 * 8;
        #pragma unroll
        for (int j = 0; j < 8; ++j) kv8[j] = kp[j];
    }
    float kn = par[(size_t)b * 8 + 6];
    const short* mb = memb + (size_t)b * Nn * Mm;
    #pragma unroll
    for (int it = 0; it < 8; ++it) {
        int n = ch * 256 + it * 32 + w * 8 + rg;
        u16x8 uv = *(const u16x8*)(mb + (size_t)n * 64 + m8 * 8);
        float dot = 0.f, ss = 0.f;
        #pragma unroll
        for (int j = 0; j < 8; ++j) {
            float x = bf2f(uv[j]);
            dot += x * kv8[j];
            ss  += x * x;
        }
        dot += __shfl_xor(dot, 1, 64); ss += __shfl_xor(ss, 1, 64);
        dot += __shfl_xor(dot, 2, 64); ss += __shfl_xor(ss, 2, 64);
        dot += __shfl_xor(dot, 4, 64); ss += __shfl_xor(ss, 4, 64);
        if (m8 == 0) cosv[(size_t)b * Nn + n] = dot / fmaxf(kn * sqrtf(ss), 1e-8f);
    }
}

// ---------------- kernel 6: M_out = mem*(1 - w*e) + w*a (wide, nt loads/stores)
template <int BF16SRC>
__global__ __launch_bounds__(256) void mout_kernel(
    const float* __restrict__ mem, const short* __restrict__ memb,
    const float* __restrict__ head, const float* __restrict__ ea,
    float* __restrict__ out)
{
    const size_t total8 = (size_t)Bb * Nn * Mm / 8;
    for (size_t i8 = (size_t)blockIdx.x * 256 + threadIdx.x; i8 < total8;
         i8 += (size_t)2048 * 256) {
        size_t row = i8 >> 3;
        int m8 = (int)(i8 & 7);
        int b = (int)(row >> 11);
        float w = head[row];
        float x[8];
        if (BF16SRC) {
            u16x8 uv = __builtin_nontemporal_load((const u16x8*)memb + i8);
            #pragma unroll
            for (int j = 0; j < 8; ++j) x[j] = bf2f(uv[j]);
        } else {
            f32x4 lo = __builtin_nontemporal_load((const f32x4*)mem + i8 * 2);
            f32x4 hi = __builtin_nontemporal_load((const f32x4*)mem + i8 * 2 + 1);
            #pragma unroll
            for (int j = 0; j < 4; ++j) { x[j] = lo[j]; x[4 + j] = hi[j]; }
        }
        const float* ep = ea + (size_t)b * 128 + m8 * 8;
        const float* ap = ep + 64;
        f32x4 o0, o1;
        #pragma unroll
        for (int j = 0; j < 4; ++j) {
            o0[j] = x[j] * (1.f - w * ep[j]) + w * ap[j];
            o1[j] = x[4 + j] * (1.f - w * ep[4 + j]) + w * ap[4 + j];
        }
        __builtin_nontemporal_store(o0, (f32x4*)out + i8 * 2);
        __builtin_nontemporal_store(o1, (f32x4*)out + i8 * 2 + 1);
    }
}

extern "C" void kernel_launch(void* const* d_in, const int* in_sizes, int n_in,
                              void* d_out, int out_size, void* d_ws, size_t ws_size,
                              hipStream_t stream)
{
    const float* inp   = (const float*)d_in[0];
    const float* h_tm1 = (const float*)d_in[1];
    const float* c_tm1 = (const float*)d_in[2];
    const float* rh0   = (const float*)d_in[3];
    const float* wh0   = (const float*)d_in[4];
    const float* mem   = (const float*)d_in[5];
    const float* W_ih  = (const float*)d_in[6];
    const float* W_hh  = (const float*)d_in[7];
    const float* b_ih  = (const float*)d_in[8];
    const float* b_hh  = (const float*)d_in[9];
    const float* W_rk  = (const float*)d_in[10];
    const float* b_rk  = (const float*)d_in[11];
    const float* W_wk  = (const float*)d_in[12];
    const float* b_wk  = (const float*)d_in[13];
    const float* W_rc  = (const float*)d_in[14];
    const float* b_rc  = (const float*)d_in[15];
    const float* W_wc  = (const float*)d_in[16];
    const float* b_wc  = (const float*)d_in[17];
    const float* W_rs  = (const float*)d_in[18];
    const float* b_rs  = (const float*)d_in[19];
    const float* W_ws  = (const float*)d_in[20];
    const float* b_ws  = (const float*)d_in[21];
    const float* W_w   = (const float*)d_in[22];
    const float* b_w   = (const float*)d_in[23];

    float* out   = (float*)d_out;
    float* h_t   = out;                         // B*H
    float* c_t   = out + 131072;                // B*H
    float* rhead = out + 262144;                // B*N
    float* whead = out + 786432;                // B*N
    float* mo    = out + 1310720;               // B*N*M = 33554432 f
    // scratch in the dead M_out region (all consumed before mout writes):
    float* cosbuf = mo;                         //  0.50M f
    float* zbuf   = mo + 524288;                //  0.50M f
    short* Ab     = (short*)(mo + 1048576);     //  212992 bf16
    short* Wb     = (short*)(mo + 1179648);     // 1703936 bf16 (ends 2031616 f)

    float* ws  = (float*)d_ws;
    float* kk  = ws;               // B*M   = 16384 f
    float* par = ws + 16384;       // B*8   =  2048 f
    float* ea  = ws + 18432;       // B*2M  = 32768 f  (ends 51200 f)

    const size_t memb_elems = (size_t)Bb * Nn * Mm;            // 33.5M shorts
    const bool big_ws = ws_size >= (size_t)51200 * 4 + memb_elems * 2;
    short* memb = big_ws ? (short*)(ws + 51200)
                         : (short*)(mo + 2097152);             // ends 18874368 f
    float* psc  = mo + 18874368;   // B*8*64 = 131072 f, dead both ways, used pre-mout

    // 1: read head params (blocks 0..255) || convW (blocks 256..1087)
    headparams_convW_kernel<<<1088, 256, 0, stream>>>(
        h_tm1, W_rk, b_rk, W_rc, b_rc, W_rs, b_rs, kk, par, W_ih, W_hh, Wb);
    // 2: mem -> bf16 + read cosine (wide sweep)
    convM_cos_kernel<<<2048, 256, 0, stream>>>(mem, kk, par, cosbuf, memb);
    // 3: read address (per-batch, small traffic)
    address_kernel<<<Bb, 1024, 0, stream>>>(cosbuf, par, rh0, rhead);
    // 3b: wide M_read partial sums
    mread_partial_kernel<<<2048, 256, 0, stream>>>(memb, rhead, psc);
    // 3c: reduce partials + build A
    convA_kernel<<<Bb, 128, 0, stream>>>(psc, inp, h_tm1, Ab);
    // 4: LSTM GEMM (MFMA, LDS-free)
    lstm_gemm_mfma<<<dim3(4, 32), 256, 0, stream>>>(Ab, Wb, b_ih, b_hh, zbuf);
    // 5: gates + write head params + wvec (per-batch)
    gates_wparams_kernel<<<Bb, 1024, 0, stream>>>(
        zbuf, c_tm1, W_wk, b_wk, W_wc, b_wc, W_ws, b_ws, W_w, b_w,
        h_t, c_t, kk, par, ea);
    // 5b: wide write cosine
    wcos_kernel<<<2048, 256, 0, stream>>>(memb, kk, par, cosbuf);
    // 5c: write address (per-batch)
    address_kernel<<<Bb, 1024, 0, stream>>>(cosbuf, par, wh0, whead);
    // 6: memory update
    if (big_ws)
        mout_kernel<1><<<2048, 256, 0, stream>>>(mem, memb, whead, ea, mo);
    else
        mout_kernel<0><<<2048, 256, 0, stream>>>(mem, memb, whead, ea, mo);
}

// Round 12
// 153.290 us; speedup vs baseline: 1.0462x; 1.0462x over previous
//
#include <hip/hip_runtime.h>
#include <hip/hip_bf16.h>

// NTM single step. B=256, D=256, H=512, M=64, N=2048, S=3, SHIFTS=(1,0,-1)
#define Bb 256
#define Hh 512
#define Mm 64
#define Nn 2048

typedef __attribute__((ext_vector_type(8))) short bf16x8;
typedef __attribute__((ext_vector_type(4))) float f32x4;
typedef __attribute__((ext_vector_type(4))) unsigned short u16x4;
typedef __attribute__((ext_vector_type(8))) unsigned short u16x8;

static __device__ __forceinline__ short f2bf(float f) {
    unsigned u = __float_as_uint(f);
    unsigned r = (u + 0x7FFFu + ((u >> 16) & 1u)) >> 16;
    return (short)r;
}
static __device__ __forceinline__ float bf2f(unsigned short u) {
    return __uint_as_float(((unsigned)u) << 16);
}

// ---------------- kernel 1: read-path head params (tiny, gates the cos sweep)
__global__ __launch_bounds__(256) void head_params_kernel(
    const float* __restrict__ h,
    const float* __restrict__ Wk, const float* __restrict__ bk,
    const float* __restrict__ Wc, const float* __restrict__ bc,
    const float* __restrict__ Ws, const float* __restrict__ bs,
    float* __restrict__ kk, float* __restrict__ par)
{
    int b = blockIdx.x;
    __shared__ float hs[Hh];
    __shared__ float red[6];
    __shared__ float skk[Mm];
    const float* hb = h + (size_t)b * Hh;
    for (int i = threadIdx.x; i < Hh; i += 256) hs[i] = hb[i];
    __syncthreads();
    int m = threadIdx.x >> 2, sub = threadIdx.x & 3;
    {
        const float* w = Wk + (size_t)m * Hh + sub * 128;
        const float* hh = hs + sub * 128;
        float acc = 0.f;
        #pragma unroll 8
        for (int k = 0; k < 128; ++k) acc += hh[k] * w[k];
        acc += __shfl_xor(acc, 1, 64);
        acc += __shfl_xor(acc, 2, 64);
        if (sub == 0) {
            float v = tanhf(acc + bk[m]);
            kk[(size_t)b * Mm + m] = v;
            skk[m] = v;
        }
    }
    if (threadIdx.x < 24) {
        int o = threadIdx.x >> 2, su = threadIdx.x & 3;
        const float* w = ((o < 3) ? (Wc + (size_t)o * Hh) : (Ws + (size_t)(o - 3) * Hh)) + su * 128;
        const float* hh = hs + su * 128;
        float acc = 0.f;
        #pragma unroll 8
        for (int k = 0; k < 128; ++k) acc += hh[k] * w[k];
        acc += __shfl_xor(acc, 1, 64);
        acc += __shfl_xor(acc, 2, 64);
        if (su == 0) red[o] = acc + ((o < 3) ? bc[o] : bs[o - 3]);
    }
    __syncthreads();
    if (threadIdx.x == 0) {
        float beta  = fmaxf(red[0], 0.f) + 1e-4f;
        float g     = 1.f / (1.f + __expf(-red[1]));
        float gamma = fmaxf(red[2], 0.f) + 1.0001f;
        float l0 = red[3], l1 = red[4], l2 = red[5];
        float mx = fmaxf(l0, fmaxf(l1, l2));
        float e0 = __expf(l0 - mx), e1 = __expf(l1 - mx), e2 = __expf(l2 - mx);
        float inv = 1.f / (e0 + e1 + e2);
        float ssq = 0.f;
        #pragma unroll
        for (int i = 0; i < Mm; ++i) ssq += skk[i] * skk[i];
        float* p = par + (size_t)b * 8;
        p[0] = beta; p[1] = g; p[2] = gamma;
        p[3] = e0 * inv; p[4] = e1 * inv; p[5] = e2 * inv;
        p[6] = sqrtf(ssq);
    }
}

// ---------------- kernel 2: blocks 0..2047: mem f32->bf16 + read cosine (wide);
//                  blocks 2048..2879: convW (hidden under the BW-bound sweep)
__global__ __launch_bounds__(256) void convM_cos_convW_kernel(
    const float* __restrict__ mem, const float* __restrict__ kk,
    const float* __restrict__ par, float* __restrict__ cosv,
    short* __restrict__ memb,
    const float* __restrict__ W_ih, const float* __restrict__ W_hh,
    short* __restrict__ Wb)
{
    if (blockIdx.x >= 2048) {
        unsigned g = (blockIdx.x - 2048) * 256 + threadIdx.x;
        unsigned j = g / 104u;
        unsigned kq = (g - j * 104u) * 8u;
        const float* src = (kq < 320u) ? (W_ih + (size_t)j * 320 + kq)
                                       : (W_hh + (size_t)j * 512 + (kq - 320u));
        float4 a = ((const float4*)src)[0];
        float4 c = ((const float4*)src)[1];
        bf16x8 o;
        o[0] = f2bf(a.x); o[1] = f2bf(a.y); o[2] = f2bf(a.z); o[3] = f2bf(a.w);
        o[4] = f2bf(c.x); o[5] = f2bf(c.y); o[6] = f2bf(c.z); o[7] = f2bf(c.w);
        *(bf16x8*)(Wb + (size_t)j * 832 + kq) = o;
        return;
    }
    int b  = blockIdx.x >> 3;
    int n0 = (blockIdx.x & 7) << 8;
    int w  = threadIdx.x >> 6;
    int l  = threadIdx.x & 63;
    int m4 = l & 15;
    int rq = l >> 4;

    float4 kv = ((const float4*)(kk + (size_t)b * Mm))[m4];
    float kn = par[(size_t)b * 8 + 6];
    const f32x4* mb4 = (const f32x4*)(mem + (size_t)b * Nn * Mm);
    short* ob = memb + (size_t)b * Nn * Mm;

    #pragma unroll
    for (int q = 0; q < 16; ++q) {
        int n = n0 + w * 64 + q * 4 + rq;
        f32x4 v = __builtin_nontemporal_load(mb4 + (size_t)n * 16 + m4);
        u16x4 o;
        o[0] = (unsigned short)f2bf(v[0]); o[1] = (unsigned short)f2bf(v[1]);
        o[2] = (unsigned short)f2bf(v[2]); o[3] = (unsigned short)f2bf(v[3]);
        *(u16x4*)(ob + (size_t)n * 64 + m4 * 4) = o;   // keep cached (reused 3x)
        float dot = v[0] * kv.x + v[1] * kv.y + v[2] * kv.z + v[3] * kv.w;
        float ss  = v[0] * v[0] + v[1] * v[1] + v[2] * v[2] + v[3] * v[3];
        dot += __shfl_xor(dot, 1, 64); ss += __shfl_xor(ss, 1, 64);
        dot += __shfl_xor(dot, 2, 64); ss += __shfl_xor(ss, 2, 64);
        dot += __shfl_xor(dot, 4, 64); ss += __shfl_xor(ss, 4, 64);
        dot += __shfl_xor(dot, 8, 64); ss += __shfl_xor(ss, 8, 64);
        if (m4 == 0) cosv[(size_t)b * Nn + n] = dot / fmaxf(kn * sqrtf(ss), 1e-8f);
    }
}

// ---------------- kernel 3: read address + M_read (16B bf16 loads) + A-matrix build
__global__ __launch_bounds__(1024) void raddr_mread_convA_kernel(
    const float* __restrict__ cosv, const float* __restrict__ par,
    const float* __restrict__ prev, const short* __restrict__ memb,
    const float* __restrict__ inp, const float* __restrict__ h,
    float* __restrict__ outh, short* __restrict__ Ab)
{
    int b = blockIdx.x;
    int t = threadIdx.x;
    int w = t >> 6, l = t & 63;
    __shared__ float csh[Nn];
    __shared__ float redw[16];
    __shared__ float redM[128][8][8];   // 32 KB
    __shared__ float mrdL[Mm];

    const float* pv = par + (size_t)b * 8;
    float beta = pv[0], g = pv[1], gamma = pv[2];
    float s0 = pv[3], s1 = pv[4], s2 = pv[5];

    float v0 = beta * cosv[(size_t)b * Nn + t];
    float v1 = beta * cosv[(size_t)b * Nn + t + 1024];
    float mx = fmaxf(v0, v1);
    #pragma unroll
    for (int msk = 1; msk < 64; msk <<= 1) mx = fmaxf(mx, __shfl_xor(mx, msk, 64));
    if (l == 0) redw[w] = mx;
    __syncthreads();
    mx = redw[0];
    #pragma unroll
    for (int i = 1; i < 16; ++i) mx = fmaxf(mx, redw[i]);
    float e0 = __expf(v0 - mx), e1 = __expf(v1 - mx);
    float sum = e0 + e1;
    #pragma unroll
    for (int msk = 1; msk < 64; msk <<= 1) sum += __shfl_xor(sum, msk, 64);
    __syncthreads();
    if (l == 0) redw[w] = sum;
    __syncthreads();
    sum = 0.f;
    #pragma unroll
    for (int i = 0; i < 16; ++i) sum += redw[i];
    float invs = 1.f / sum;
    const float* pb = prev + (size_t)b * Nn;
    float i0 = g * e0 * invs + (1.f - g) * pb[t];
    float i1 = g * e1 * invs + (1.f - g) * pb[t + 1024];
    csh[t] = i0; csh[t + 1024] = i1;
    __syncthreads();
    int n1 = t + 1024;
    float c0 = s0 * csh[(t + 1) & (Nn - 1)] + s1 * i0 + s2 * csh[(t - 1) & (Nn - 1)];
    float c1 = s0 * csh[(n1 + 1) & (Nn - 1)] + s1 * i1 + s2 * csh[(n1 - 1) & (Nn - 1)];
    float p0 = exp2f(gamma * __log2f(c0));
    float p1 = exp2f(gamma * __log2f(c1));
    float osum = p0 + p1;
    #pragma unroll
    for (int msk = 1; msk < 64; msk <<= 1) osum += __shfl_xor(osum, msk, 64);
    __syncthreads();
    if (l == 0) redw[w] = osum;
    __syncthreads();
    osum = 0.f;
    #pragma unroll
    for (int i = 0; i < 16; ++i) osum += redw[i];
    float inv2 = 1.f / osum;
    float h0 = p0 * inv2, h1 = p1 * inv2;
    outh[(size_t)b * Nn + t] = h0;
    outh[(size_t)b * Nn + n1] = h1;
    __syncthreads();
    csh[t] = h0; csh[n1] = h1;
    __syncthreads();

    // M_read from bf16 copy: 16B loads, lane m8 owns 8 cols, 128 row-threads
    int m8 = t & 7;
    int r  = t >> 3;                      // 0..127
    const short* mb = memb + (size_t)b * Nn * Mm;
    float acc[8] = {};
    #pragma unroll 4
    for (int it = 0; it < 16; ++it) {
        int n = it * 128 + r;
        float wgt = csh[n];
        u16x8 uv = *(const u16x8*)(mb + (size_t)n * 64 + m8 * 8);
        #pragma unroll
        for (int j = 0; j < 8; ++j) acc[j] += wgt * bf2f(uv[j]);
    }
    #pragma unroll
    for (int j = 0; j < 8; ++j) redM[r][m8][j] = acc[j];
    __syncthreads();
    #pragma unroll
    for (int s = 64; s >= 1; s >>= 1) {
        if (r < s) {
            #pragma unroll
            for (int j = 0; j < 8; ++j) redM[r][m8][j] += redM[r + s][m8][j];
        }
        __syncthreads();
    }
    if (t < 8) {
        #pragma unroll
        for (int j = 0; j < 8; ++j) mrdL[t * 8 + j] = redM[0][t][j];
    }
    __syncthreads();

    if (t < 104) {
        int kq = t * 8;
        float v[8];
        if (kq < 256) {
            const float* s = inp + (size_t)b * 256 + kq;
            #pragma unroll
            for (int i = 0; i < 8; ++i) v[i] = s[i];
        } else if (kq < 320) {
            #pragma unroll
            for (int i = 0; i < 8; ++i) v[i] = mrdL[kq - 256 + i];
        } else {
            const float* s = h + (size_t)b * 512 + (kq - 320);
            #pragma unroll
            for (int i = 0; i < 8; ++i) v[i] = s[i];
        }
        bf16x8 o;
        #pragma unroll
        for (int i = 0; i < 8; ++i) o[i] = f2bf(v[i]);
        *(bf16x8*)(Ab + (size_t)b * 832 + kq) = o;
    }
}

// ---------------- kernel 4: MFMA GEMM, LDS-free (operands L2/L3-resident)
__global__ __launch_bounds__(256) void lstm_gemm_mfma(
    const short* __restrict__ Ab, const short* __restrict__ Wb,
    const float* __restrict__ b_ih, const float* __restrict__ b_hh,
    float* __restrict__ z)
{
    int t = threadIdx.x;
    int r0 = blockIdx.x * 64, c0 = blockIdx.y * 64;
    int w = t >> 6, l = t & 63;
    int wr = (w >> 1) * 32, wc = (w & 1) * 32;
    int lr = l & 15, kb = (l >> 4) * 8;

    const short* A0 = Ab + (size_t)(r0 + wr + lr) * 832 + kb;
    const short* A1 = A0 + 16 * 832;
    const short* B0 = Wb + (size_t)(c0 + wc + lr) * 832 + kb;
    const short* B1 = B0 + 16 * 832;

    f32x4 acc00 = {0.f, 0.f, 0.f, 0.f}, acc01 = {0.f, 0.f, 0.f, 0.f};
    f32x4 acc10 = {0.f, 0.f, 0.f, 0.f}, acc11 = {0.f, 0.f, 0.f, 0.f};

    #pragma unroll 2
    for (int kt = 0; kt < 26; ++kt) {
        int k0 = kt * 32;
        bf16x8 a0 = *(const bf16x8*)(A0 + k0);
        bf16x8 a1 = *(const bf16x8*)(A1 + k0);
        bf16x8 b0 = *(const bf16x8*)(B0 + k0);
        bf16x8 b1 = *(const bf16x8*)(B1 + k0);
        acc00 = __builtin_amdgcn_mfma_f32_16x16x32_bf16(a0, b0, acc00, 0, 0, 0);
        acc01 = __builtin_amdgcn_mfma_f32_16x16x32_bf16(a0, b1, acc01, 0, 0, 0);
        acc10 = __builtin_amdgcn_mfma_f32_16x16x32_bf16(a1, b0, acc10, 0, 0, 0);
        acc11 = __builtin_amdgcn_mfma_f32_16x16x32_bf16(a1, b1, acc11, 0, 0, 0);
    }
    int rq = (l >> 4) * 4;
    #pragma unroll
    for (int q = 0; q < 4; ++q) {
        int row0 = r0 + wr + rq + q;
        int col0 = c0 + wc + lr;
        z[(size_t)row0 * 2048 + col0] = acc00[q] + b_ih[col0] + b_hh[col0];
        z[(size_t)row0 * 2048 + col0 + 16] = acc01[q] + b_ih[col0 + 16] + b_hh[col0 + 16];
        z[(size_t)(row0 + 16) * 2048 + col0] = acc10[q] + b_ih[col0] + b_hh[col0];
        z[(size_t)(row0 + 16) * 2048 + col0 + 16] = acc11[q] + b_ih[col0 + 16] + b_hh[col0 + 16];
    }
}

// ---------------- kernel 5: gates + write head params + wvec + write cosine + waddr
__global__ __launch_bounds__(1024) void gates_wfused_kernel(
    const float* __restrict__ z, const float* __restrict__ c_tm1,
    const float* __restrict__ Wk, const float* __restrict__ bk,
    const float* __restrict__ Wc, const float* __restrict__ bc,
    const float* __restrict__ Ws, const float* __restrict__ bs,
    const float* __restrict__ W_w, const float* __restrict__ b_w,
    const short* __restrict__ memb, const float* __restrict__ prev,
    float* __restrict__ h_out, float* __restrict__ c_out,
    float* __restrict__ ea, float* __restrict__ outh)
{
    int b = blockIdx.x;
    int t = threadIdx.x;
    int w = t >> 6, l = t & 63;
    __shared__ float hs[Hh];
    __shared__ float red6[6];
    __shared__ float skk[Mm];
    __shared__ float parL[8];
    __shared__ float csh[Nn];
    __shared__ float redw[16];

    // ---- gates
    if (t < 512) {
        const float* zb = z + (size_t)b * 2048;
        float zi = zb[t], zf = zb[512 + t], zg = zb[1024 + t], zo = zb[1536 + t];
        float si = 1.f / (1.f + __expf(-zi));
        float sf = 1.f / (1.f + __expf(-zf));
        float so = 1.f / (1.f + __expf(-zo));
        float ct = sf * c_tm1[(size_t)b * 512 + t] + si * tanhf(zg);
        float ht = so * tanhf(ct);
        c_out[(size_t)b * 512 + t] = ct;
        h_out[(size_t)b * 512 + t] = ht;
        hs[t] = ht;
    }
    __syncthreads();

    // ---- write-path head params + write vector
    if (t < 256) {
        int m = t >> 2, sub = t & 3;
        const float* wv = Wk + (size_t)m * Hh + sub * 128;
        const float* hh = hs + sub * 128;
        float acc = 0.f;
        #pragma unroll 8
        for (int k = 0; k < 128; ++k) acc += hh[k] * wv[k];
        acc += __shfl_xor(acc, 1, 64);
        acc += __shfl_xor(acc, 2, 64);
        if (sub == 0) skk[m] = tanhf(acc + bk[m]);
    } else if (t < 280) {
        int o = (t - 256) >> 2, su = t & 3;
        const float* wv = ((o < 3) ? (Wc + (size_t)o * Hh) : (Ws + (size_t)(o - 3) * Hh)) + su * 128;
        const float* hh = hs + su * 128;
        float acc = 0.f;
        #pragma unroll 8
        for (int k = 0; k < 128; ++k) acc += hh[k] * wv[k];
        acc += __shfl_xor(acc, 1, 64);
        acc += __shfl_xor(acc, 2, 64);
        if (su == 0) red6[o] = acc + ((o < 3) ? bc[o] : bs[o - 3]);
    } else if (t >= 512) {
        int o = (t - 512) >> 2, su = t & 3;
        const float* wv = W_w + (size_t)o * Hh + su * 128;
        const float* hh = hs + su * 128;
        float acc = 0.f;
        #pragma unroll 8
        for (int k = 0; k < 128; ++k) acc += hh[k] * wv[k];
        acc += __shfl_xor(acc, 1, 64);
        acc += __shfl_xor(acc, 2, 64);
        if (su == 0) {
            float v = acc + b_w[o];
            ea[(size_t)b * 128 + o] = (o < Mm) ? (1.f / (1.f + __expf(-v))) : tanhf(v);
        }
    }
    __syncthreads();
    if (t < 64) {
        float v = skk[t];
        float ssq = v * v;
        #pragma unroll
        for (int msk = 1; msk < 64; msk <<= 1) ssq += __shfl_xor(ssq, msk, 64);
        if (t == 0) {
            parL[6] = sqrtf(ssq);
            parL[0] = fmaxf(red6[0], 0.f) + 1e-4f;
            parL[1] = 1.f / (1.f + __expf(-red6[1]));
            parL[2] = fmaxf(red6[2], 0.f) + 1.0001f;
            float l0 = red6[3], l1 = red6[4], l2 = red6[5];
            float mx = fmaxf(l0, fmaxf(l1, l2));
            float e0 = __expf(l0 - mx), e1 = __expf(l1 - mx), e2 = __expf(l2 - mx);
            float inv = 1.f / (e0 + e1 + e2);
            parL[3] = e0 * inv; parL[4] = e1 * inv; parL[5] = e2 * inv;
        }
    }
    __syncthreads();

    // ---- write cosine (bf16 memb, 16B loads)
    {
        int m8 = l & 7, rg = l >> 3;
        float kv8[8];
        #pragma unroll
        for (int j = 0; j < 8; ++j) kv8[j] = skk[m8 * 8 + j];
        float kn = parL[6];
        const short* mb = memb + (size_t)b * Nn * Mm;
        #pragma unroll 4
        for (int it = 0; it < 16; ++it) {
            int n = it * 128 + w * 8 + rg;
            u16x8 uv = *(const u16x8*)(mb + (size_t)n * 64 + m8 * 8);
            float dot = 0.f, ss = 0.f;
            #pragma unroll
            for (int j = 0; j < 8; ++j) {
                float x = bf2f(uv[j]);
                dot += x * kv8[j];
                ss  += x * x;
            }
            dot += __shfl_xor(dot, 1, 64); ss += __shfl_xor(ss, 1, 64);
            dot += __shfl_xor(dot, 2, 64); ss += __shfl_xor(ss, 2, 64);
            dot += __shfl_xor(dot, 4, 64); ss += __shfl_xor(ss, 4, 64);
            if (m8 == 0) csh[n] = dot / fmaxf(kn * sqrtf(ss), 1e-8f);
        }
    }
    __syncthreads();

    // ---- write address
    {
        float beta = parL[0], g = parL[1], gamma = parL[2];
        float s0 = parL[3], s1 = parL[4], s2 = parL[5];
        float v0 = beta * csh[t], v1 = beta * csh[t + 1024];
        float mx = fmaxf(v0, v1);
        #pragma unroll
        for (int msk = 1; msk < 64; msk <<= 1) mx = fmaxf(mx, __shfl_xor(mx, msk, 64));
        if (l == 0) redw[w] = mx;
        __syncthreads();
        mx = redw[0];
        #pragma unroll
        for (int i = 1; i < 16; ++i) mx = fmaxf(mx, redw[i]);
        float e0 = __expf(v0 - mx), e1 = __expf(v1 - mx);
        float sum = e0 + e1;
        #pragma unroll
        for (int msk = 1; msk < 64; msk <<= 1) sum += __shfl_xor(sum, msk, 64);
        __syncthreads();
        if (l == 0) redw[w] = sum;
        __syncthreads();
        sum = 0.f;
        #pragma unroll
        for (int i = 0; i < 16; ++i) sum += redw[i];
        float invs = 1.f / sum;
        const float* pb = prev + (size_t)b * Nn;
        float i0 = g * e0 * invs + (1.f - g) * pb[t];
        float i1 = g * e1 * invs + (1.f - g) * pb[t + 1024];
        __syncthreads();
        csh[t] = i0; csh[t + 1024] = i1;
        __syncthreads();
        int n1 = t + 1024;
        float c0 = s0 * csh[(t + 1) & (Nn - 1)] + s1 * i0 + s2 * csh[(t - 1) & (Nn - 1)];
        float c1 = s0 * csh[(n1 + 1) & (Nn - 1)] + s1 * i1 + s2 * csh[(n1 - 1) & (Nn - 1)];
        float p0 = exp2f(gamma * __log2f(c0));
        float p1 = exp2f(gamma * __log2f(c1));
        float osum = p0 + p1;
        #pragma unroll
        for (int msk = 1; msk < 64; msk <<= 1) osum += __shfl_xor(osum, msk, 64);
        __syncthreads();
        if (l == 0) redw[w] = osum;
        __syncthreads();
        osum = 0.f;
        #pragma unroll
        for (int i = 0; i < 16; ++i) osum += redw[i];
        float inv2 = 1.f / osum;
        outh[(size_t)b * Nn + t] = p0 * inv2;
        outh[(size_t)b * Nn + n1] = p1 * inv2;
    }
}

// ---------------- kernel 6: M_out = mem*(1 - w*e) + w*a (wide, nt loads/stores)
template <int BF16SRC>
__global__ __launch_bounds__(256) void mout_kernel(
    const float* __restrict__ mem, const short* __restrict__ memb,
    const float* __restrict__ head, const float* __restrict__ ea,
    float* __restrict__ out)
{
    const size_t total8 = (size_t)Bb * Nn * Mm / 8;
    for (size_t i8 = (size_t)blockIdx.x * 256 + threadIdx.x; i8 < total8;
         i8 += (size_t)2048 * 256) {
        size_t row = i8 >> 3;
        int m8 = (int)(i8 & 7);
        int b = (int)(row >> 11);
        float w = head[row];
        float x[8];
        if (BF16SRC) {
            u16x8 uv = __builtin_nontemporal_load((const u16x8*)memb + i8);
            #pragma unroll
            for (int j = 0; j < 8; ++j) x[j] = bf2f(uv[j]);
        } else {
            f32x4 lo = __builtin_nontemporal_load((const f32x4*)mem + i8 * 2);
            f32x4 hi = __builtin_nontemporal_load((const f32x4*)mem + i8 * 2 + 1);
            #pragma unroll
            for (int j = 0; j < 4; ++j) { x[j] = lo[j]; x[4 + j] = hi[j]; }
        }
        const float* ep = ea + (size_t)b * 128 + m8 * 8;
        const float* ap = ep + 64;
        f32x4 o0, o1;
        #pragma unroll
        for (int j = 0; j < 4; ++j) {
            o0[j] = x[j] * (1.f - w * ep[j]) + w * ap[j];
            o1[j] = x[4 + j] * (1.f - w * ep[4 + j]) + w * ap[4 + j];
        }
        __builtin_nontemporal_store(o0, (f32x4*)out + i8 * 2);
        __builtin_nontemporal_store(o1, (f32x4*)out + i8 * 2 + 1);
    }
}

extern "C" void kernel_launch(void* const* d_in, const int* in_sizes, int n_in,
                              void* d_out, int out_size, void* d_ws, size_t ws_size,
                              hipStream_t stream)
{
    const float* inp   = (const float*)d_in[0];
    const float* h_tm1 = (const float*)d_in[1];
    const float* c_tm1 = (const float*)d_in[2];
    const float* rh0   = (const float*)d_in[3];
    const float* wh0   = (const float*)d_in[4];
    const float* mem   = (const float*)d_in[5];
    const float* W_ih  = (const float*)d_in[6];
    const float* W_hh  = (const float*)d_in[7];
    const float* b_ih  = (const float*)d_in[8];
    const float* b_hh  = (const float*)d_in[9];
    const float* W_rk  = (const float*)d_in[10];
    const float* b_rk  = (const float*)d_in[11];
    const float* W_wk  = (const float*)d_in[12];
    const float* b_wk  = (const float*)d_in[13];
    const float* W_rc  = (const float*)d_in[14];
    const float* b_rc  = (const float*)d_in[15];
    const float* W_wc  = (const float*)d_in[16];
    const float* b_wc  = (const float*)d_in[17];
    const float* W_rs  = (const float*)d_in[18];
    const float* b_rs  = (const float*)d_in[19];
    const float* W_ws  = (const float*)d_in[20];
    const float* b_ws  = (const float*)d_in[21];
    const float* W_w   = (const float*)d_in[22];
    const float* b_w   = (const float*)d_in[23];

    float* out   = (float*)d_out;
    float* h_t   = out;                         // B*H
    float* c_t   = out + 131072;                // B*H
    float* rhead = out + 262144;                // B*N
    float* whead = out + 786432;                // B*N
    float* mo    = out + 1310720;               // B*N*M = 33554432 f
    // scratch in the dead M_out region (all consumed before mout writes):
    float* cosbuf = mo;                         //  0.50M f
    float* zbuf   = mo + 524288;                //  0.50M f
    short* Ab     = (short*)(mo + 1048576);     //  212992 bf16
    short* Wb     = (short*)(mo + 1179648);     // 1703936 bf16 (ends 2.03M f)

    float* ws  = (float*)d_ws;
    float* kk  = ws;               // B*M   = 16384 f
    float* par = ws + 16384;       // B*8   =  2048 f
    float* ea  = ws + 18432;       // B*2M  = 32768 f  (ends 51200 f)

    const size_t memb_elems = (size_t)Bb * Nn * Mm;            // 33.5M shorts
    const bool big_ws = ws_size >= (size_t)51200 * 4 + memb_elems * 2;
    short* memb = big_ws ? (short*)(ws + 51200)
                         : (short*)(mo + 2097152);             // dead-region fallback

    // 1: read-path head params (tiny)
    head_params_kernel<<<Bb, 256, 0, stream>>>(
        h_tm1, W_rk, b_rk, W_rc, b_rc, W_rs, b_rs, kk, par);
    // 2: mem -> bf16 + read cosine, with convW riding along
    convM_cos_convW_kernel<<<2880, 256, 0, stream>>>(
        mem, kk, par, cosbuf, memb, W_ih, W_hh, Wb);
    // 3: read address + M_read + A build
    raddr_mread_convA_kernel<<<Bb, 1024, 0, stream>>>(
        cosbuf, par, rh0, memb, inp, h_tm1, rhead, Ab);
    // 4: LSTM GEMM (MFMA, LDS-free)
    lstm_gemm_mfma<<<dim3(4, 32), 256, 0, stream>>>(Ab, Wb, b_ih, b_hh, zbuf);
    // 5: gates + write head params + wvec + write cosine + write address
    gates_wfused_kernel<<<Bb, 1024, 0, stream>>>(
        zbuf, c_tm1, W_wk, b_wk, W_wc, b_wc, W_ws, b_ws, W_w, b_w,
        memb, wh0, h_t, c_t, ea, whead);
    // 6: memory update
    if (big_ws)
        mout_kernel<1><<<2048, 256, 0, stream>>>(mem, memb, whead, ea, mo);
    else
        mout_kernel<0><<<2048, 256, 0, stream>>>(mem, memb, whead, ea, mo);
}